// Round 7
// baseline (167.864 us; speedup 1.0000x reference)
//
#include <hip/hip_runtime.h>

// ---------------------------------------------------------------------------
// SelfAttention (distance-based, transposed accumulation), MI355X bf16 MFMA.
// B=4, S=2048, F=512, H=8, DH=64, OUT=512.
//
// ROUND 7 = ROUND 6 VERBATIM except pass2 gets T3-minimum 2-phase prefetch:
// q_lds/vt_lds double-buffered, stage(t+1) issued BEFORE compute(t), one
// __syncthreads per tile (its vmcnt(0)+lgkmcnt(0) drain covers both the
// prefetch and the previous tile's reads). Everything else unchanged.
// ---------------------------------------------------------------------------

typedef __attribute__((ext_vector_type(8))) short bf16x8;
typedef __attribute__((ext_vector_type(4))) float f32x4;

#define MFMA16 __builtin_amdgcn_mfma_f32_16x16x32_bf16
#define LOG2E 1.4426950408889634f
#define TWO_LOG2E 2.8853900817779268f

__device__ inline unsigned short f2bf(float f) {
  unsigned int u = __float_as_uint(f);
  unsigned int r = 0x7fffu + ((u >> 16) & 1u);
  return (unsigned short)((u + r) >> 16);
}
__device__ inline float bf2f(unsigned short h) {
  return __uint_as_float(((unsigned int)h) << 16);
}
__device__ inline float fexp2(float x) { return __builtin_amdgcn_exp2f(x); }

// async global->LDS, 16B per lane. lds base must be wave-uniform.
__device__ inline void gl_lds16(const unsigned short* g, unsigned short* lds) {
  __builtin_amdgcn_global_load_lds(
      (const __attribute__((address_space(1))) unsigned int*)g,
      (__attribute__((address_space(3))) unsigned int*)lds, 16, 0, 0);
}

// ---------------------------------------------------------------------------
// prep: cast x to bf16, pack W^T (bf16) for qkv and out proj, pack biases.
// (round 6 verbatim)
// ---------------------------------------------------------------------------
#define NXB (8192*512)
#define NWQ (1536*512)
#define NWO (512*512)

__global__ __launch_bounds__(256) void prep(
    const float* __restrict__ x, const float* __restrict__ Wq,
    const float* __restrict__ Wk, const float* __restrict__ Wv,
    const float* __restrict__ Wo, const float* __restrict__ bq,
    const float* __restrict__ bk, const float* __restrict__ bv,
    unsigned short* __restrict__ xb, unsigned short* __restrict__ wqkvT,
    unsigned short* __restrict__ woT, float* __restrict__ biasp) {
  int i = blockIdx.x * blockDim.x + threadIdx.x;
  if (i < NXB) { xb[i] = f2bf(x[i]); return; }
  i -= NXB;
  if (i < NWQ) {  // wqkvT[n][f] = W(f, n%512), n in [0,1536)
    int n = i >> 9, f = i & 511;
    const float* W = (n < 512) ? Wq : (n < 1024) ? Wk : Wv;
    wqkvT[i] = f2bf(W[f * 512 + (n & 511)]);
    return;
  }
  i -= NWQ;
  if (i < NWO) {  // woT[o][hd] = Wo[hd][o]
    int o = i >> 9, hd = i & 511;
    woT[i] = f2bf(Wo[hd * 512 + o]);
    return;
  }
  i -= NWO;
  if (i < 1536) {
    biasp[i] = (i < 512) ? bq[i] : (i < 1024) ? bk[i - 512] : bv[i - 1024];
  }
}

// ---------------------------------------------------------------------------
// GEMM C[M,N] = A[M,K] * Bt[N,K]^T + bias (round 6 verbatim).
// MODE 0: scatter bf16 into q~/k/v [bh][s][d].  MODE 1: bias+leakyrelu f32.
// ---------------------------------------------------------------------------
template<int MODE>
__global__ __launch_bounds__(256) void gemm_bt(
    const unsigned short* __restrict__ A, const unsigned short* __restrict__ Bt,
    const float* __restrict__ bias,
    unsigned short* __restrict__ o_q, unsigned short* __restrict__ o_k,
    unsigned short* __restrict__ o_v, float* __restrict__ o_f, int K) {
  const int m0 = blockIdx.y * 128;
  const int n0 = blockIdx.x * 128;
  const int tid = threadIdx.x;
  const int w = tid >> 6, l = tid & 63, lg = l >> 4, ll = l & 15;
  const int wr = w >> 1, wc = w & 1;
  __shared__ unsigned short a_lds[128 * 32];
  __shared__ unsigned short b_lds[128 * 32];
  f32x4 acc[4][4] = {};
  const int nkt = K >> 5;
  for (int kt = 0; kt < nkt; ++kt) {
#pragma unroll
    for (int c = 0; c < 2; ++c) {
      const int cc_base = c * 256 + w * 64;
      const int cc = cc_base + l;
      const int row = cc >> 2, cl = cc & 3;
      gl_lds16(A + (size_t)(m0 + row) * K + kt * 32 + cl * 8, a_lds + cc_base * 8);
      gl_lds16(Bt + (size_t)(n0 + row) * K + kt * 32 + cl * 8, b_lds + cc_base * 8);
    }
    __syncthreads();
    bf16x8 af[4], bfr[4];
#pragma unroll
    for (int mi = 0; mi < 4; ++mi)
      af[mi] = *(const bf16x8*)(a_lds + (wr * 64 + mi * 16 + ll) * 32 + lg * 8);
#pragma unroll
    for (int ni = 0; ni < 4; ++ni)
      bfr[ni] = *(const bf16x8*)(b_lds + (wc * 64 + ni * 16 + ll) * 32 + lg * 8);
#pragma unroll
    for (int mi = 0; mi < 4; ++mi)
#pragma unroll
      for (int ni = 0; ni < 4; ++ni)
        acc[mi][ni] = MFMA16(af[mi], bfr[ni], acc[mi][ni], 0, 0, 0);
    __syncthreads();
  }
#pragma unroll
  for (int mi = 0; mi < 4; ++mi)
#pragma unroll
    for (int ni = 0; ni < 4; ++ni) {
      const int col = n0 + wc * 64 + ni * 16 + ll;
      const float bb = bias[col];
#pragma unroll
      for (int r = 0; r < 4; ++r) {
        const int row = m0 + wr * 64 + mi * 16 + lg * 4 + r;
        float v = acc[mi][ni][r] + bb;
        if (MODE == 0) {
          const int which = col >> 9, h = (col >> 6) & 7, d = col & 63;
          const int b = row >> 11, s = row & 2047;
          if (which == 0) v *= TWO_LOG2E;  // q prescale
          const size_t idx = ((size_t)((b * 8 + h) * 2048 + s)) * 64 + d;
          (which == 0 ? o_q : which == 1 ? o_k : o_v)[idx] = f2bf(v);
        } else {
          v = v >= 0.f ? v : 0.01f * v;
          o_f[(size_t)row * 512 + col] = v;
        }
      }
    }
}

// ---------------------------------------------------------------------------
// k2l[row] = log2e * sum_d k[row][d]^2   (round 6 verbatim)
// ---------------------------------------------------------------------------
__global__ __launch_bounds__(256) void k2_kernel(const unsigned short* __restrict__ k_g,
                                                 float* __restrict__ k2l_g) {
  const int lane = threadIdx.x & 63;
  const int wid = (blockIdx.x * blockDim.x + threadIdx.x) >> 6;
  const int nw = (gridDim.x * blockDim.x) >> 6;
  for (int row = wid; row < 32 * 2048; row += nw) {
    float v = bf2f(k_g[(size_t)row * 64 + lane]);
    v *= v;
#pragma unroll
    for (int m = 1; m < 64; m <<= 1) v += __shfl_xor(v, m);
    if (lane == 0) k2l_g[row] = LOG2E * v;
  }
}

// ---------------------------------------------------------------------------
// transpose_v: vT~[bh][d][s] = invl[s] * v[bh][s][d]  (round 6 verbatim)
// ---------------------------------------------------------------------------
__global__ __launch_bounds__(256) void transpose_v(const unsigned short* __restrict__ v_g,
                                                   const float* __restrict__ invl_g,
                                                   unsigned short* __restrict__ vt_g) {
  const int bh = blockIdx.x >> 5, st = blockIdx.x & 31;
  const int s0 = st * 64;
  __shared__ unsigned short tile[64][72];
  const int t = threadIdx.x;
  {
    const int sl = t >> 2, cg = t & 3;
    const float sc = invl_g[bh * 2048 + s0 + sl];
    const unsigned short* src = v_g + ((size_t)(bh * 2048 + s0 + sl)) * 64 + cg * 16;
    bf16x8 v0 = *(const bf16x8*)(src);
    bf16x8 v1 = *(const bf16x8*)(src + 8);
#pragma unroll
    for (int e = 0; e < 8; ++e) tile[sl][cg * 16 + e] = f2bf(sc * bf2f((unsigned short)v0[e]));
#pragma unroll
    for (int e = 0; e < 8; ++e) tile[sl][cg * 16 + 8 + e] = f2bf(sc * bf2f((unsigned short)v1[e]));
  }
  __syncthreads();
  {
    const int dl = t >> 2, sg = t & 3;
    bf16x8 o0, o1;
#pragma unroll
    for (int e = 0; e < 8; ++e) o0[e] = (short)tile[sg * 16 + e][dl];
#pragma unroll
    for (int e = 0; e < 8; ++e) o1[e] = (short)tile[sg * 16 + 8 + e][dl];
    unsigned short* dst = vt_g + ((size_t)(bh * 64 + dl)) * 2048 + s0 + sg * 16;
    *(bf16x8*)dst = o0;
    *(bf16x8*)(dst + 8) = o1;
  }
}

// ---------------------------------------------------------------------------
// pass1: invl[i] = 1 / sum_j exp2(q~_i.k_j - k2l[j])  (round 6 verbatim)
// ---------------------------------------------------------------------------
__global__ __launch_bounds__(256) void pass1(const unsigned short* __restrict__ q_g,
                                             const unsigned short* __restrict__ k_g,
                                             const float* __restrict__ k2l_g,
                                             float* __restrict__ invl_g) {
  const int bh = blockIdx.x >> 5, ib = blockIdx.x & 31;
  const int i0 = ib * 64;
  const int tid = threadIdx.x, w = tid >> 6, l = tid & 63, lg = l >> 4, ll = l & 15;
  __shared__ unsigned short k_lds[64 * 64];
  __shared__ float k2_lds[64];
  const unsigned short* qrow = q_g + ((size_t)(bh * 2048 + i0 + w * 16 + ll)) * 64;
  const bf16x8 qa0 = *(const bf16x8*)(qrow + lg * 8);
  const bf16x8 qa1 = *(const bf16x8*)(qrow + 32 + lg * 8);
  float lrun[4] = {0.f, 0.f, 0.f, 0.f};
  for (int jt = 0; jt < 32; ++jt) {
    const int j0 = jt * 64;
#pragma unroll
    for (int c = 0; c < 2; ++c) {
      const int cc_base = c * 256 + w * 64;
      const int cc = cc_base + l;
      const int row = cc >> 3, cl = cc & 7;
      gl_lds16(k_g + ((size_t)(bh * 2048 + j0 + row)) * 64 + ((cl ^ (row & 7)) * 8),
               k_lds + cc_base * 8);
    }
    if (tid < 64) k2_lds[tid] = k2l_g[bh * 2048 + j0 + tid];
    __syncthreads();
#pragma unroll
    for (int nf = 0; nf < 4; ++nf) {
      const int jr = nf * 16 + ll;
      const unsigned short* kb = k_lds + jr * 64;
      const int sw = jr & 7;
      bf16x8 b0 = *(const bf16x8*)(kb + ((lg ^ sw) * 8));
      bf16x8 b1 = *(const bf16x8*)(kb + (((4 + lg) ^ sw) * 8));
      f32x4 sa = {};
      sa = MFMA16(qa0, b0, sa, 0, 0, 0);
      sa = MFMA16(qa1, b1, sa, 0, 0, 0);
      const float k2v = k2_lds[jr];
      lrun[0] += fexp2(sa[0] - k2v);
      lrun[1] += fexp2(sa[1] - k2v);
      lrun[2] += fexp2(sa[2] - k2v);
      lrun[3] += fexp2(sa[3] - k2v);
    }
    __syncthreads();
  }
#pragma unroll
  for (int r = 0; r < 4; ++r) {
    float t = lrun[r];
#pragma unroll
    for (int m = 1; m < 16; m <<= 1) t += __shfl_xor(t, m);
    if (ll == 0) invl_g[bh * 2048 + i0 + w * 16 + lg * 4 + r] = 1.f / t;
  }
}

// ---------------------------------------------------------------------------
// pass2: attn[j,d] = sum_i exp2(q~_i.k_j - k2l[j]) * v~[i,d]
// Round-6 body with 2-phase prefetch: q_lds/vt_lds double-buffered,
// stage(t+1) issued before compute(t), one __syncthreads per tile.
// ---------------------------------------------------------------------------
__global__ __launch_bounds__(256) void pass2(const unsigned short* __restrict__ q_g,
                                             const unsigned short* __restrict__ k_g,
                                             const unsigned short* __restrict__ vt_g,
                                             const float* __restrict__ k2l_g,
                                             unsigned short* __restrict__ attnb) {
  const int bh = blockIdx.x >> 5, jb = blockIdx.x & 31;
  const int j0 = jb * 64;
  const int tid = threadIdx.x, w = tid >> 6, l = tid & 63, lg = l >> 4, ll = l & 15;
  __shared__ unsigned short q_lds[2][64 * 64];
  __shared__ unsigned short vt_lds[2][64 * 64];
  __shared__ unsigned short p_lds[64 * 64];
  const unsigned short* q_base = q_g + (size_t)bh * 2048 * 64;
  const unsigned short* vt_base = vt_g + (size_t)bh * 64 * 2048;
  // K A-frags: rows j = j0 + w*16 + ll, in registers for whole kernel
  const unsigned short* krow = k_g + ((size_t)(bh * 2048 + j0 + w * 16 + ll)) * 64;
  const bf16x8 ka0 = *(const bf16x8*)(krow + lg * 8);
  const bf16x8 ka1 = *(const bf16x8*)(krow + 32 + lg * 8);
  float k2v[4];
#pragma unroll
  for (int r = 0; r < 4; ++r) k2v[r] = k2l_g[bh * 2048 + j0 + w * 16 + lg * 4 + r];
  f32x4 oacc[4] = {};
  // prologue: stage it=0 into buf 0
#pragma unroll
  for (int c = 0; c < 2; ++c) {
    const int cc_base = c * 256 + w * 64;
    const int cc = cc_base + l;
    const int row = cc >> 3, cl = cc & 7;
    const int csw = (cl ^ (row & 7)) * 8;
    gl_lds16(q_base + (size_t)row * 64 + csw, &q_lds[0][cc_base * 8]);
    gl_lds16(vt_base + (size_t)row * 2048 + csw, &vt_lds[0][cc_base * 8]);
  }
  __syncthreads();
  for (int it = 0; it < 32; ++it) {
    const int slot = it & 1;
    if (it + 1 < 32) {
      const int i1 = (it + 1) * 64;
#pragma unroll
      for (int c = 0; c < 2; ++c) {
        const int cc_base = c * 256 + w * 64;
        const int cc = cc_base + l;
        const int row = cc >> 3, cl = cc & 7;
        const int csw = (cl ^ (row & 7)) * 8;
        gl_lds16(q_base + (size_t)(i1 + row) * 64 + csw, &q_lds[slot ^ 1][cc_base * 8]);
        gl_lds16(vt_base + (size_t)row * 2048 + i1 + csw, &vt_lds[slot ^ 1][cc_base * 8]);
      }
    }
    // scores ST[j,i] and P^T -> LDS  (round-6 body, reading buf[slot])
#pragma unroll
    for (int nf = 0; nf < 4; ++nf) {
      const int ir = nf * 16 + ll;
      const unsigned short* qb = &q_lds[slot][ir * 64];
      const int sw = ir & 7;
      bf16x8 b0 = *(const bf16x8*)(qb + ((lg ^ sw) * 8));
      bf16x8 b1 = *(const bf16x8*)(qb + (((4 + lg) ^ sw) * 8));
      f32x4 sa = {};
      sa = MFMA16(ka0, b0, sa, 0, 0, 0);
      sa = MFMA16(ka1, b1, sa, 0, 0, 0);
#pragma unroll
      for (int r = 0; r < 4; ++r) {
        const float p = fexp2(sa[r] - k2v[r]);
        const int j = w * 16 + lg * 4 + r;
        p_lds[j * 64 + (ir ^ ((j & 7) << 3))] = f2bf(p);
      }
    }
    // PV: A = P^T (own wave's 16 rows; within-wave LDS dependency, no barrier)
    {
      const int jr = w * 16 + ll;
      const unsigned short* pb = p_lds + jr * 64;
      const int swp = jr & 7;
      bf16x8 pa0 = *(const bf16x8*)(pb + ((lg ^ swp) * 8));
      bf16x8 pa1 = *(const bf16x8*)(pb + (((4 + lg) ^ swp) * 8));
#pragma unroll
      for (int nf = 0; nf < 4; ++nf) {
        const int dr = nf * 16 + ll;
        const unsigned short* vb = &vt_lds[slot][dr * 64];
        const int sw = dr & 7;
        bf16x8 v0 = *(const bf16x8*)(vb + ((lg ^ sw) * 8));
        bf16x8 v1 = *(const bf16x8*)(vb + (((4 + lg) ^ sw) * 8));
        oacc[nf] = MFMA16(pa0, v0, oacc[nf], 0, 0, 0);
        oacc[nf] = MFMA16(pa1, v1, oacc[nf], 0, 0, 0);
      }
    }
    __syncthreads();
  }
  const int b = bh >> 3, h2 = bh & 7;
#pragma unroll
  for (int nf = 0; nf < 4; ++nf) {
    const int d = nf * 16 + ll;
#pragma unroll
    for (int r = 0; r < 4; ++r) {
      const int j = j0 + w * 16 + lg * 4 + r;
      attnb[((size_t)(b * 2048 + j)) * 512 + h2 * 64 + d] = f2bf(oacc[nf][r]);
    }
  }
}

// ---------------------------------------------------------------------------
extern "C" void kernel_launch(void* const* d_in, const int* in_sizes, int n_in,
                              void* d_out, int out_size, void* d_ws, size_t ws_size,
                              hipStream_t stream) {
  const float* x  = (const float*)d_in[0];
  const float* Wq = (const float*)d_in[1];
  const float* bq = (const float*)d_in[2];
  const float* Wk = (const float*)d_in[3];
  const float* bk = (const float*)d_in[4];
  const float* Wv = (const float*)d_in[5];
  const float* bv = (const float*)d_in[6];
  const float* Wo = (const float*)d_in[7];
  const float* bo = (const float*)d_in[8];
  float* out = (float*)d_out;
  char* ws = (char*)d_ws;

  unsigned short* xb    = (unsigned short*)(ws);
  unsigned short* wqkvT = (unsigned short*)(ws + 8388608);
  unsigned short* woT   = (unsigned short*)(ws + 9961472);
  float*          biasp = (float*)         (ws + 10485760);
  unsigned short* q_g   = (unsigned short*)(ws + 10493952);
  unsigned short* k_g   = (unsigned short*)(ws + 18882560);
  unsigned short* v_g   = (unsigned short*)(ws + 27271168);
  unsigned short* vt_g  = (unsigned short*)(ws + 35659776);
  float*          k2_g  = (float*)         (ws + 44048384);
  float*          invl_g= (float*)         (ws + 44310528);
  unsigned short* attnb = (unsigned short*)(ws + 44572672);
  if (ws_size < (size_t)52961280) return;

  prep<<<20486, 256, 0, stream>>>(x, Wq, Wk, Wv, Wo, bq, bk, bv, xb, wqkvT, woT, biasp);
  gemm_bt<0><<<dim3(12, 64), 256, 0, stream>>>(xb, wqkvT, biasp, q_g, k_g, v_g, nullptr, 512);
  k2_kernel<<<1024, 256, 0, stream>>>(k_g, k2_g);
  pass1<<<1024, 256, 0, stream>>>(q_g, k_g, k2_g, invl_g);
  transpose_v<<<1024, 256, 0, stream>>>(v_g, invl_g, vt_g);
  pass2<<<1024, 256, 0, stream>>>(q_g, k_g, vt_g, k2_g, attnb);
  gemm_bt<1><<<dim3(4, 64), 256, 0, stream>>>(attnb, woT, bo, nullptr, nullptr, nullptr, out, 512);
}

// Round 8
// 166.215 us; speedup vs baseline: 1.0099x; 1.0099x over previous
//
#include <hip/hip_runtime.h>

// ---------------------------------------------------------------------------
// SelfAttention (distance-based, transposed accumulation), MI355X bf16 MFMA.
// B=4, S=2048, F=512, H=8, DH=64, OUT=512.
//
// ROUND 8 = ROUND 7 VERBATIM except:
//  - pass2 stores P to LDS via truncation (u>>16, 1 VALU) instead of
//    round-nearest f2bf (4 VALU): P is renormalized downstream, bias ~0.2%.
//  - prep vectorizes the x->bf16 path (float4 in, ushort4 out).
// ---------------------------------------------------------------------------

typedef __attribute__((ext_vector_type(8))) short bf16x8;
typedef __attribute__((ext_vector_type(4))) float f32x4;
typedef __attribute__((ext_vector_type(4))) unsigned short u16x4;

#define MFMA16 __builtin_amdgcn_mfma_f32_16x16x32_bf16
#define LOG2E 1.4426950408889634f
#define TWO_LOG2E 2.8853900817779268f

__device__ inline unsigned short f2bf(float f) {
  unsigned int u = __float_as_uint(f);
  unsigned int r = 0x7fffu + ((u >> 16) & 1u);
  return (unsigned short)((u + r) >> 16);
}
__device__ inline float bf2f(unsigned short h) {
  return __uint_as_float(((unsigned int)h) << 16);
}
__device__ inline float fexp2(float x) { return __builtin_amdgcn_exp2f(x); }

// async global->LDS, 16B per lane. lds base must be wave-uniform.
__device__ inline void gl_lds16(const unsigned short* g, unsigned short* lds) {
  __builtin_amdgcn_global_load_lds(
      (const __attribute__((address_space(1))) unsigned int*)g,
      (__attribute__((address_space(3))) unsigned int*)lds, 16, 0, 0);
}

// ---------------------------------------------------------------------------
// prep: cast x to bf16 (vectorized x4), pack W^T for qkv/out proj, biases.
// ---------------------------------------------------------------------------
#define NXB4 (8192*512/4)
#define NWQ (1536*512)
#define NWO (512*512)

__global__ __launch_bounds__(256) void prep(
    const float* __restrict__ x, const float* __restrict__ Wq,
    const float* __restrict__ Wk, const float* __restrict__ Wv,
    const float* __restrict__ Wo, const float* __restrict__ bq,
    const float* __restrict__ bk, const float* __restrict__ bv,
    unsigned short* __restrict__ xb, unsigned short* __restrict__ wqkvT,
    unsigned short* __restrict__ woT, float* __restrict__ biasp) {
  int i = blockIdx.x * blockDim.x + threadIdx.x;
  if (i < NXB4) {
    f32x4 v = ((const f32x4*)x)[i];
    u16x4 o;
    o.x = f2bf(v.x); o.y = f2bf(v.y); o.z = f2bf(v.z); o.w = f2bf(v.w);
    ((u16x4*)xb)[i] = o;
    return;
  }
  i -= NXB4;
  if (i < NWQ) {  // wqkvT[n][f] = W(f, n%512), n in [0,1536)
    int n = i >> 9, f = i & 511;
    const float* W = (n < 512) ? Wq : (n < 1024) ? Wk : Wv;
    wqkvT[i] = f2bf(W[f * 512 + (n & 511)]);
    return;
  }
  i -= NWQ;
  if (i < NWO) {  // woT[o][hd] = Wo[hd][o]
    int o = i >> 9, hd = i & 511;
    woT[i] = f2bf(Wo[hd * 512 + o]);
    return;
  }
  i -= NWO;
  if (i < 1536) {
    biasp[i] = (i < 512) ? bq[i] : (i < 1024) ? bk[i - 512] : bv[i - 1024];
  }
}

// ---------------------------------------------------------------------------
// GEMM C[M,N] = A[M,K] * Bt[N,K]^T + bias (round 7 verbatim).
// MODE 0: scatter bf16 into q~/k/v [bh][s][d].  MODE 1: bias+leakyrelu f32.
// ---------------------------------------------------------------------------
template<int MODE>
__global__ __launch_bounds__(256) void gemm_bt(
    const unsigned short* __restrict__ A, const unsigned short* __restrict__ Bt,
    const float* __restrict__ bias,
    unsigned short* __restrict__ o_q, unsigned short* __restrict__ o_k,
    unsigned short* __restrict__ o_v, float* __restrict__ o_f, int K) {
  const int m0 = blockIdx.y * 128;
  const int n0 = blockIdx.x * 128;
  const int tid = threadIdx.x;
  const int w = tid >> 6, l = tid & 63, lg = l >> 4, ll = l & 15;
  const int wr = w >> 1, wc = w & 1;
  __shared__ unsigned short a_lds[128 * 32];
  __shared__ unsigned short b_lds[128 * 32];
  f32x4 acc[4][4] = {};
  const int nkt = K >> 5;
  for (int kt = 0; kt < nkt; ++kt) {
#pragma unroll
    for (int c = 0; c < 2; ++c) {
      const int cc_base = c * 256 + w * 64;
      const int cc = cc_base + l;
      const int row = cc >> 2, cl = cc & 3;
      gl_lds16(A + (size_t)(m0 + row) * K + kt * 32 + cl * 8, a_lds + cc_base * 8);
      gl_lds16(Bt + (size_t)(n0 + row) * K + kt * 32 + cl * 8, b_lds + cc_base * 8);
    }
    __syncthreads();
    bf16x8 af[4], bfr[4];
#pragma unroll
    for (int mi = 0; mi < 4; ++mi)
      af[mi] = *(const bf16x8*)(a_lds + (wr * 64 + mi * 16 + ll) * 32 + lg * 8);
#pragma unroll
    for (int ni = 0; ni < 4; ++ni)
      bfr[ni] = *(const bf16x8*)(b_lds + (wc * 64 + ni * 16 + ll) * 32 + lg * 8);
#pragma unroll
    for (int mi = 0; mi < 4; ++mi)
#pragma unroll
      for (int ni = 0; ni < 4; ++ni)
        acc[mi][ni] = MFMA16(af[mi], bfr[ni], acc[mi][ni], 0, 0, 0);
    __syncthreads();
  }
#pragma unroll
  for (int mi = 0; mi < 4; ++mi)
#pragma unroll
    for (int ni = 0; ni < 4; ++ni) {
      const int col = n0 + wc * 64 + ni * 16 + ll;
      const float bb = bias[col];
#pragma unroll
      for (int r = 0; r < 4; ++r) {
        const int row = m0 + wr * 64 + mi * 16 + lg * 4 + r;
        float v = acc[mi][ni][r] + bb;
        if (MODE == 0) {
          const int which = col >> 9, h = (col >> 6) & 7, d = col & 63;
          const int b = row >> 11, s = row & 2047;
          if (which == 0) v *= TWO_LOG2E;  // q prescale
          const size_t idx = ((size_t)((b * 8 + h) * 2048 + s)) * 64 + d;
          (which == 0 ? o_q : which == 1 ? o_k : o_v)[idx] = f2bf(v);
        } else {
          v = v >= 0.f ? v : 0.01f * v;
          o_f[(size_t)row * 512 + col] = v;
        }
      }
    }
}

// ---------------------------------------------------------------------------
// k2l[row] = log2e * sum_d k[row][d]^2   (round 7 verbatim)
// ---------------------------------------------------------------------------
__global__ __launch_bounds__(256) void k2_kernel(const unsigned short* __restrict__ k_g,
                                                 float* __restrict__ k2l_g) {
  const int lane = threadIdx.x & 63;
  const int wid = (blockIdx.x * blockDim.x + threadIdx.x) >> 6;
  const int nw = (gridDim.x * blockDim.x) >> 6;
  for (int row = wid; row < 32 * 2048; row += nw) {
    float v = bf2f(k_g[(size_t)row * 64 + lane]);
    v *= v;
#pragma unroll
    for (int m = 1; m < 64; m <<= 1) v += __shfl_xor(v, m);
    if (lane == 0) k2l_g[row] = LOG2E * v;
  }
}

// ---------------------------------------------------------------------------
// transpose_v: vT~[bh][d][s] = invl[s] * v[bh][s][d]  (round 7 verbatim)
// ---------------------------------------------------------------------------
__global__ __launch_bounds__(256) void transpose_v(const unsigned short* __restrict__ v_g,
                                                   const float* __restrict__ invl_g,
                                                   unsigned short* __restrict__ vt_g) {
  const int bh = blockIdx.x >> 5, st = blockIdx.x & 31;
  const int s0 = st * 64;
  __shared__ unsigned short tile[64][72];
  const int t = threadIdx.x;
  {
    const int sl = t >> 2, cg = t & 3;
    const float sc = invl_g[bh * 2048 + s0 + sl];
    const unsigned short* src = v_g + ((size_t)(bh * 2048 + s0 + sl)) * 64 + cg * 16;
    bf16x8 v0 = *(const bf16x8*)(src);
    bf16x8 v1 = *(const bf16x8*)(src + 8);
#pragma unroll
    for (int e = 0; e < 8; ++e) tile[sl][cg * 16 + e] = f2bf(sc * bf2f((unsigned short)v0[e]));
#pragma unroll
    for (int e = 0; e < 8; ++e) tile[sl][cg * 16 + 8 + e] = f2bf(sc * bf2f((unsigned short)v1[e]));
  }
  __syncthreads();
  {
    const int dl = t >> 2, sg = t & 3;
    bf16x8 o0, o1;
#pragma unroll
    for (int e = 0; e < 8; ++e) o0[e] = (short)tile[sg * 16 + e][dl];
#pragma unroll
    for (int e = 0; e < 8; ++e) o1[e] = (short)tile[sg * 16 + 8 + e][dl];
    unsigned short* dst = vt_g + ((size_t)(bh * 64 + dl)) * 2048 + s0 + sg * 16;
    *(bf16x8*)dst = o0;
    *(bf16x8*)(dst + 8) = o1;
  }
}

// ---------------------------------------------------------------------------
// pass1: invl[i] = 1 / sum_j exp2(q~_i.k_j - k2l[j])  (round 7 verbatim)
// ---------------------------------------------------------------------------
__global__ __launch_bounds__(256) void pass1(const unsigned short* __restrict__ q_g,
                                             const unsigned short* __restrict__ k_g,
                                             const float* __restrict__ k2l_g,
                                             float* __restrict__ invl_g) {
  const int bh = blockIdx.x >> 5, ib = blockIdx.x & 31;
  const int i0 = ib * 64;
  const int tid = threadIdx.x, w = tid >> 6, l = tid & 63, lg = l >> 4, ll = l & 15;
  __shared__ unsigned short k_lds[64 * 64];
  __shared__ float k2_lds[64];
  const unsigned short* qrow = q_g + ((size_t)(bh * 2048 + i0 + w * 16 + ll)) * 64;
  const bf16x8 qa0 = *(const bf16x8*)(qrow + lg * 8);
  const bf16x8 qa1 = *(const bf16x8*)(qrow + 32 + lg * 8);
  float lrun[4] = {0.f, 0.f, 0.f, 0.f};
  for (int jt = 0; jt < 32; ++jt) {
    const int j0 = jt * 64;
#pragma unroll
    for (int c = 0; c < 2; ++c) {
      const int cc_base = c * 256 + w * 64;
      const int cc = cc_base + l;
      const int row = cc >> 3, cl = cc & 7;
      gl_lds16(k_g + ((size_t)(bh * 2048 + j0 + row)) * 64 + ((cl ^ (row & 7)) * 8),
               k_lds + cc_base * 8);
    }
    if (tid < 64) k2_lds[tid] = k2l_g[bh * 2048 + j0 + tid];
    __syncthreads();
#pragma unroll
    for (int nf = 0; nf < 4; ++nf) {
      const int jr = nf * 16 + ll;
      const unsigned short* kb = k_lds + jr * 64;
      const int sw = jr & 7;
      bf16x8 b0 = *(const bf16x8*)(kb + ((lg ^ sw) * 8));
      bf16x8 b1 = *(const bf16x8*)(kb + (((4 + lg) ^ sw) * 8));
      f32x4 sa = {};
      sa = MFMA16(qa0, b0, sa, 0, 0, 0);
      sa = MFMA16(qa1, b1, sa, 0, 0, 0);
      const float k2v = k2_lds[jr];
      lrun[0] += fexp2(sa[0] - k2v);
      lrun[1] += fexp2(sa[1] - k2v);
      lrun[2] += fexp2(sa[2] - k2v);
      lrun[3] += fexp2(sa[3] - k2v);
    }
    __syncthreads();
  }
#pragma unroll
  for (int r = 0; r < 4; ++r) {
    float t = lrun[r];
#pragma unroll
    for (int m = 1; m < 16; m <<= 1) t += __shfl_xor(t, m);
    if (ll == 0) invl_g[bh * 2048 + i0 + w * 16 + lg * 4 + r] = 1.f / t;
  }
}

// ---------------------------------------------------------------------------
// pass2: attn[j,d] = sum_i exp2(q~_i.k_j - k2l[j]) * v~[i,d]
// Round-7 structure (dbuf prefetch); P stored via truncation (u>>16).
// ---------------------------------------------------------------------------
__global__ __launch_bounds__(256) void pass2(const unsigned short* __restrict__ q_g,
                                             const unsigned short* __restrict__ k_g,
                                             const unsigned short* __restrict__ vt_g,
                                             const float* __restrict__ k2l_g,
                                             unsigned short* __restrict__ attnb) {
  const int bh = blockIdx.x >> 5, jb = blockIdx.x & 31;
  const int j0 = jb * 64;
  const int tid = threadIdx.x, w = tid >> 6, l = tid & 63, lg = l >> 4, ll = l & 15;
  __shared__ unsigned short q_lds[2][64 * 64];
  __shared__ unsigned short vt_lds[2][64 * 64];
  __shared__ unsigned short p_lds[64 * 64];
  const unsigned short* q_base = q_g + (size_t)bh * 2048 * 64;
  const unsigned short* vt_base = vt_g + (size_t)bh * 64 * 2048;
  // K A-frags: rows j = j0 + w*16 + ll, in registers for whole kernel
  const unsigned short* krow = k_g + ((size_t)(bh * 2048 + j0 + w * 16 + ll)) * 64;
  const bf16x8 ka0 = *(const bf16x8*)(krow + lg * 8);
  const bf16x8 ka1 = *(const bf16x8*)(krow + 32 + lg * 8);
  float k2v[4];
#pragma unroll
  for (int r = 0; r < 4; ++r) k2v[r] = k2l_g[bh * 2048 + j0 + w * 16 + lg * 4 + r];
  f32x4 oacc[4] = {};
  // prologue: stage it=0 into buf 0
#pragma unroll
  for (int c = 0; c < 2; ++c) {
    const int cc_base = c * 256 + w * 64;
    const int cc = cc_base + l;
    const int row = cc >> 3, cl = cc & 7;
    const int csw = (cl ^ (row & 7)) * 8;
    gl_lds16(q_base + (size_t)row * 64 + csw, &q_lds[0][cc_base * 8]);
    gl_lds16(vt_base + (size_t)row * 2048 + csw, &vt_lds[0][cc_base * 8]);
  }
  __syncthreads();
  for (int it = 0; it < 32; ++it) {
    const int slot = it & 1;
    if (it + 1 < 32) {
      const int i1 = (it + 1) * 64;
#pragma unroll
      for (int c = 0; c < 2; ++c) {
        const int cc_base = c * 256 + w * 64;
        const int cc = cc_base + l;
        const int row = cc >> 3, cl = cc & 7;
        const int csw = (cl ^ (row & 7)) * 8;
        gl_lds16(q_base + (size_t)(i1 + row) * 64 + csw, &q_lds[slot ^ 1][cc_base * 8]);
        gl_lds16(vt_base + (size_t)row * 2048 + i1 + csw, &vt_lds[slot ^ 1][cc_base * 8]);
      }
    }
    // scores ST[j,i] and P^T -> LDS  (truncating bf16 store)
#pragma unroll
    for (int nf = 0; nf < 4; ++nf) {
      const int ir = nf * 16 + ll;
      const unsigned short* qb = &q_lds[slot][ir * 64];
      const int sw = ir & 7;
      bf16x8 b0 = *(const bf16x8*)(qb + ((lg ^ sw) * 8));
      bf16x8 b1 = *(const bf16x8*)(qb + (((4 + lg) ^ sw) * 8));
      f32x4 sa = {};
      sa = MFMA16(ka0, b0, sa, 0, 0, 0);
      sa = MFMA16(ka1, b1, sa, 0, 0, 0);
#pragma unroll
      for (int r = 0; r < 4; ++r) {
        const float p = fexp2(sa[r] - k2v[r]);
        const int j = w * 16 + lg * 4 + r;
        p_lds[j * 64 + (ir ^ ((j & 7) << 3))] =
            (unsigned short)(__float_as_uint(p) >> 16);
      }
    }
    // PV: A = P^T (own wave's 16 rows; within-wave LDS dependency, no barrier)
    {
      const int jr = w * 16 + ll;
      const unsigned short* pb = p_lds + jr * 64;
      const int swp = jr & 7;
      bf16x8 pa0 = *(const bf16x8*)(pb + ((lg ^ swp) * 8));
      bf16x8 pa1 = *(const bf16x8*)(pb + (((4 + lg) ^ swp) * 8));
#pragma unroll
      for (int nf = 0; nf < 4; ++nf) {
        const int dr = nf * 16 + ll;
        const unsigned short* vb = &vt_lds[slot][dr * 64];
        const int sw = dr & 7;
        bf16x8 v0 = *(const bf16x8*)(vb + ((lg ^ sw) * 8));
        bf16x8 v1 = *(const bf16x8*)(vb + (((4 + lg) ^ sw) * 8));
        oacc[nf] = MFMA16(pa0, v0, oacc[nf], 0, 0, 0);
        oacc[nf] = MFMA16(pa1, v1, oacc[nf], 0, 0, 0);
      }
    }
    __syncthreads();
  }
  const int b = bh >> 3, h2 = bh & 7;
#pragma unroll
  for (int nf = 0; nf < 4; ++nf) {
    const int d = nf * 16 + ll;
#pragma unroll
    for (int r = 0; r < 4; ++r) {
      const int j = j0 + w * 16 + lg * 4 + r;
      attnb[((size_t)(b * 2048 + j)) * 512 + h2 * 64 + d] = f2bf(oacc[nf][r]);
    }
  }
}

// ---------------------------------------------------------------------------
extern "C" void kernel_launch(void* const* d_in, const int* in_sizes, int n_in,
                              void* d_out, int out_size, void* d_ws, size_t ws_size,
                              hipStream_t stream) {
  const float* x  = (const float*)d_in[0];
  const float* Wq = (const float*)d_in[1];
  const float* bq = (const float*)d_in[2];
  const float* Wk = (const float*)d_in[3];
  const float* bk = (const float*)d_in[4];
  const float* Wv = (const float*)d_in[5];
  const float* bv = (const float*)d_in[6];
  const float* Wo = (const float*)d_in[7];
  const float* bo = (const float*)d_in[8];
  float* out = (float*)d_out;
  char* ws = (char*)d_ws;

  unsigned short* xb    = (unsigned short*)(ws);
  unsigned short* wqkvT = (unsigned short*)(ws + 8388608);
  unsigned short* woT   = (unsigned short*)(ws + 9961472);
  float*          biasp = (float*)         (ws + 10485760);
  unsigned short* q_g   = (unsigned short*)(ws + 10493952);
  unsigned short* k_g   = (unsigned short*)(ws + 18882560);
  unsigned short* v_g   = (unsigned short*)(ws + 27271168);
  unsigned short* vt_g  = (unsigned short*)(ws + 35659776);
  float*          k2_g  = (float*)         (ws + 44048384);
  float*          invl_g= (float*)         (ws + 44310528);
  unsigned short* attnb = (unsigned short*)(ws + 44572672);
  if (ws_size < (size_t)52961280) return;

  prep<<<8199, 256, 0, stream>>>(x, Wq, Wk, Wv, Wo, bq, bk, bv, xb, wqkvT, woT, biasp);
  gemm_bt<0><<<dim3(12, 64), 256, 0, stream>>>(xb, wqkvT, biasp, q_g, k_g, v_g, nullptr, 512);
  k2_kernel<<<1024, 256, 0, stream>>>(k_g, k2_g);
  pass1<<<1024, 256, 0, stream>>>(q_g, k_g, k2_g, invl_g);
  transpose_v<<<1024, 256, 0, stream>>>(v_g, invl_g, vt_g);
  pass2<<<1024, 256, 0, stream>>>(q_g, k_g, vt_g, k2_g, attnb);
  gemm_bt<1><<<dim3(4, 64), 256, 0, stream>>>(attnb, woT, bo, nullptr, nullptr, nullptr, out, 512);
}

// Round 9
// 165.016 us; speedup vs baseline: 1.0173x; 1.0073x over previous
//
#include <hip/hip_runtime.h>

// ---------------------------------------------------------------------------
// SelfAttention (distance-based, transposed accumulation), MI355X bf16 MFMA.
// B=4, S=2048, F=512, H=8, DH=64, OUT=512.
//
// ROUND 9 = ROUND 8 VERBATIM except pass2 is pack-2: each wave owns 32 j
// (two 16-row sets), sharing its aq/bvf LDS fragment reads across both sets
// (halves LDS-read traffic per unit work). P goes through p_lds[128*64]
// exactly as r8 (the register-exchange path is retired: failed r3/r4/r5).
// Grid: 512 blocks (j0 = jb*128). Everything else byte-identical to r8.
// ---------------------------------------------------------------------------

typedef __attribute__((ext_vector_type(8))) short bf16x8;
typedef __attribute__((ext_vector_type(4))) float f32x4;
typedef __attribute__((ext_vector_type(4))) unsigned short u16x4;

#define MFMA16 __builtin_amdgcn_mfma_f32_16x16x32_bf16
#define LOG2E 1.4426950408889634f
#define TWO_LOG2E 2.8853900817779268f

__device__ inline unsigned short f2bf(float f) {
  unsigned int u = __float_as_uint(f);
  unsigned int r = 0x7fffu + ((u >> 16) & 1u);
  return (unsigned short)((u + r) >> 16);
}
__device__ inline float bf2f(unsigned short h) {
  return __uint_as_float(((unsigned int)h) << 16);
}
__device__ inline float fexp2(float x) { return __builtin_amdgcn_exp2f(x); }

// async global->LDS, 16B per lane. lds base must be wave-uniform.
__device__ inline void gl_lds16(const unsigned short* g, unsigned short* lds) {
  __builtin_amdgcn_global_load_lds(
      (const __attribute__((address_space(1))) unsigned int*)g,
      (__attribute__((address_space(3))) unsigned int*)lds, 16, 0, 0);
}

// ---------------------------------------------------------------------------
// prep: cast x to bf16 (vectorized x4), pack W^T for qkv/out proj, biases.
// (round 8 verbatim)
// ---------------------------------------------------------------------------
#define NXB4 (8192*512/4)
#define NWQ (1536*512)
#define NWO (512*512)

__global__ __launch_bounds__(256) void prep(
    const float* __restrict__ x, const float* __restrict__ Wq,
    const float* __restrict__ Wk, const float* __restrict__ Wv,
    const float* __restrict__ Wo, const float* __restrict__ bq,
    const float* __restrict__ bk, const float* __restrict__ bv,
    unsigned short* __restrict__ xb, unsigned short* __restrict__ wqkvT,
    unsigned short* __restrict__ woT, float* __restrict__ biasp) {
  int i = blockIdx.x * blockDim.x + threadIdx.x;
  if (i < NXB4) {
    f32x4 v = ((const f32x4*)x)[i];
    u16x4 o;
    o.x = f2bf(v.x); o.y = f2bf(v.y); o.z = f2bf(v.z); o.w = f2bf(v.w);
    ((u16x4*)xb)[i] = o;
    return;
  }
  i -= NXB4;
  if (i < NWQ) {  // wqkvT[n][f] = W(f, n%512), n in [0,1536)
    int n = i >> 9, f = i & 511;
    const float* W = (n < 512) ? Wq : (n < 1024) ? Wk : Wv;
    wqkvT[i] = f2bf(W[f * 512 + (n & 511)]);
    return;
  }
  i -= NWQ;
  if (i < NWO) {  // woT[o][hd] = Wo[hd][o]
    int o = i >> 9, hd = i & 511;
    woT[i] = f2bf(Wo[hd * 512 + o]);
    return;
  }
  i -= NWO;
  if (i < 1536) {
    biasp[i] = (i < 512) ? bq[i] : (i < 1024) ? bk[i - 512] : bv[i - 1024];
  }
}

// ---------------------------------------------------------------------------
// GEMM C[M,N] = A[M,K] * Bt[N,K]^T + bias (round 8 verbatim).
// MODE 0: scatter bf16 into q~/k/v [bh][s][d].  MODE 1: bias+leakyrelu f32.
// ---------------------------------------------------------------------------
template<int MODE>
__global__ __launch_bounds__(256) void gemm_bt(
    const unsigned short* __restrict__ A, const unsigned short* __restrict__ Bt,
    const float* __restrict__ bias,
    unsigned short* __restrict__ o_q, unsigned short* __restrict__ o_k,
    unsigned short* __restrict__ o_v, float* __restrict__ o_f, int K) {
  const int m0 = blockIdx.y * 128;
  const int n0 = blockIdx.x * 128;
  const int tid = threadIdx.x;
  const int w = tid >> 6, l = tid & 63, lg = l >> 4, ll = l & 15;
  const int wr = w >> 1, wc = w & 1;
  __shared__ unsigned short a_lds[128 * 32];
  __shared__ unsigned short b_lds[128 * 32];
  f32x4 acc[4][4] = {};
  const int nkt = K >> 5;
  for (int kt = 0; kt < nkt; ++kt) {
#pragma unroll
    for (int c = 0; c < 2; ++c) {
      const int cc_base = c * 256 + w * 64;
      const int cc = cc_base + l;
      const int row = cc >> 2, cl = cc & 3;
      gl_lds16(A + (size_t)(m0 + row) * K + kt * 32 + cl * 8, a_lds + cc_base * 8);
      gl_lds16(Bt + (size_t)(n0 + row) * K + kt * 32 + cl * 8, b_lds + cc_base * 8);
    }
    __syncthreads();
    bf16x8 af[4], bfr[4];
#pragma unroll
    for (int mi = 0; mi < 4; ++mi)
      af[mi] = *(const bf16x8*)(a_lds + (wr * 64 + mi * 16 + ll) * 32 + lg * 8);
#pragma unroll
    for (int ni = 0; ni < 4; ++ni)
      bfr[ni] = *(const bf16x8*)(b_lds + (wc * 64 + ni * 16 + ll) * 32 + lg * 8);
#pragma unroll
    for (int mi = 0; mi < 4; ++mi)
#pragma unroll
      for (int ni = 0; ni < 4; ++ni)
        acc[mi][ni] = MFMA16(af[mi], bfr[ni], acc[mi][ni], 0, 0, 0);
    __syncthreads();
  }
#pragma unroll
  for (int mi = 0; mi < 4; ++mi)
#pragma unroll
    for (int ni = 0; ni < 4; ++ni) {
      const int col = n0 + wc * 64 + ni * 16 + ll;
      const float bb = bias[col];
#pragma unroll
      for (int r = 0; r < 4; ++r) {
        const int row = m0 + wr * 64 + mi * 16 + lg * 4 + r;
        float v = acc[mi][ni][r] + bb;
        if (MODE == 0) {
          const int which = col >> 9, h = (col >> 6) & 7, d = col & 63;
          const int b = row >> 11, s = row & 2047;
          if (which == 0) v *= TWO_LOG2E;  // q prescale
          const size_t idx = ((size_t)((b * 8 + h) * 2048 + s)) * 64 + d;
          (which == 0 ? o_q : which == 1 ? o_k : o_v)[idx] = f2bf(v);
        } else {
          v = v >= 0.f ? v : 0.01f * v;
          o_f[(size_t)row * 512 + col] = v;
        }
      }
    }
}

// ---------------------------------------------------------------------------
// k2l[row] = log2e * sum_d k[row][d]^2   (round 8 verbatim)
// ---------------------------------------------------------------------------
__global__ __launch_bounds__(256) void k2_kernel(const unsigned short* __restrict__ k_g,
                                                 float* __restrict__ k2l_g) {
  const int lane = threadIdx.x & 63;
  const int wid = (blockIdx.x * blockDim.x + threadIdx.x) >> 6;
  const int nw = (gridDim.x * blockDim.x) >> 6;
  for (int row = wid; row < 32 * 2048; row += nw) {
    float v = bf2f(k_g[(size_t)row * 64 + lane]);
    v *= v;
#pragma unroll
    for (int m = 1; m < 64; m <<= 1) v += __shfl_xor(v, m);
    if (lane == 0) k2l_g[row] = LOG2E * v;
  }
}

// ---------------------------------------------------------------------------
// transpose_v: vT~[bh][d][s] = invl[s] * v[bh][s][d]  (round 8 verbatim)
// ---------------------------------------------------------------------------
__global__ __launch_bounds__(256) void transpose_v(const unsigned short* __restrict__ v_g,
                                                   const float* __restrict__ invl_g,
                                                   unsigned short* __restrict__ vt_g) {
  const int bh = blockIdx.x >> 5, st = blockIdx.x & 31;
  const int s0 = st * 64;
  __shared__ unsigned short tile[64][72];
  const int t = threadIdx.x;
  {
    const int sl = t >> 2, cg = t & 3;
    const float sc = invl_g[bh * 2048 + s0 + sl];
    const unsigned short* src = v_g + ((size_t)(bh * 2048 + s0 + sl)) * 64 + cg * 16;
    bf16x8 v0 = *(const bf16x8*)(src);
    bf16x8 v1 = *(const bf16x8*)(src + 8);
#pragma unroll
    for (int e = 0; e < 8; ++e) tile[sl][cg * 16 + e] = f2bf(sc * bf2f((unsigned short)v0[e]));
#pragma unroll
    for (int e = 0; e < 8; ++e) tile[sl][cg * 16 + 8 + e] = f2bf(sc * bf2f((unsigned short)v1[e]));
  }
  __syncthreads();
  {
    const int dl = t >> 2, sg = t & 3;
    bf16x8 o0, o1;
#pragma unroll
    for (int e = 0; e < 8; ++e) o0[e] = (short)tile[sg * 16 + e][dl];
#pragma unroll
    for (int e = 0; e < 8; ++e) o1[e] = (short)tile[sg * 16 + 8 + e][dl];
    unsigned short* dst = vt_g + ((size_t)(bh * 64 + dl)) * 2048 + s0 + sg * 16;
    *(bf16x8*)dst = o0;
    *(bf16x8*)(dst + 8) = o1;
  }
}

// ---------------------------------------------------------------------------
// pass1: invl[i] = 1 / sum_j exp2(q~_i.k_j - k2l[j])  (round 8 verbatim)
// ---------------------------------------------------------------------------
__global__ __launch_bounds__(256) void pass1(const unsigned short* __restrict__ q_g,
                                             const unsigned short* __restrict__ k_g,
                                             const float* __restrict__ k2l_g,
                                             float* __restrict__ invl_g) {
  const int bh = blockIdx.x >> 5, ib = blockIdx.x & 31;
  const int i0 = ib * 64;
  const int tid = threadIdx.x, w = tid >> 6, l = tid & 63, lg = l >> 4, ll = l & 15;
  __shared__ unsigned short k_lds[64 * 64];
  __shared__ float k2_lds[64];
  const unsigned short* qrow = q_g + ((size_t)(bh * 2048 + i0 + w * 16 + ll)) * 64;
  const bf16x8 qa0 = *(const bf16x8*)(qrow + lg * 8);
  const bf16x8 qa1 = *(const bf16x8*)(qrow + 32 + lg * 8);
  float lrun[4] = {0.f, 0.f, 0.f, 0.f};
  for (int jt = 0; jt < 32; ++jt) {
    const int j0 = jt * 64;
#pragma unroll
    for (int c = 0; c < 2; ++c) {
      const int cc_base = c * 256 + w * 64;
      const int cc = cc_base + l;
      const int row = cc >> 3, cl = cc & 7;
      gl_lds16(k_g + ((size_t)(bh * 2048 + j0 + row)) * 64 + ((cl ^ (row & 7)) * 8),
               k_lds + cc_base * 8);
    }
    if (tid < 64) k2_lds[tid] = k2l_g[bh * 2048 + j0 + tid];
    __syncthreads();
#pragma unroll
    for (int nf = 0; nf < 4; ++nf) {
      const int jr = nf * 16 + ll;
      const unsigned short* kb = k_lds + jr * 64;
      const int sw = jr & 7;
      bf16x8 b0 = *(const bf16x8*)(kb + ((lg ^ sw) * 8));
      bf16x8 b1 = *(const bf16x8*)(kb + (((4 + lg) ^ sw) * 8));
      f32x4 sa = {};
      sa = MFMA16(qa0, b0, sa, 0, 0, 0);
      sa = MFMA16(qa1, b1, sa, 0, 0, 0);
      const float k2v = k2_lds[jr];
      lrun[0] += fexp2(sa[0] - k2v);
      lrun[1] += fexp2(sa[1] - k2v);
      lrun[2] += fexp2(sa[2] - k2v);
      lrun[3] += fexp2(sa[3] - k2v);
    }
    __syncthreads();
  }
#pragma unroll
  for (int r = 0; r < 4; ++r) {
    float t = lrun[r];
#pragma unroll
    for (int m = 1; m < 16; m <<= 1) t += __shfl_xor(t, m);
    if (ll == 0) invl_g[bh * 2048 + i0 + w * 16 + lg * 4 + r] = 1.f / t;
  }
}

// ---------------------------------------------------------------------------
// pass2: attn[j,d] = sum_i exp2(q~_i.k_j - k2l[j]) * v~[i,d]
// PACK-2 on the round-8 body: each wave owns 32 j (two 16-row sets).
// Shared aq/bvf LDS fragment reads feed both sets' MFMAs. P via p_lds
// [128*64] (same swizzle). Dbuf prefetch as r8. Grid 512, j0 = jb*128.
// ---------------------------------------------------------------------------
__global__ __launch_bounds__(256) void pass2(const unsigned short* __restrict__ q_g,
                                             const unsigned short* __restrict__ k_g,
                                             const unsigned short* __restrict__ vt_g,
                                             const float* __restrict__ k2l_g,
                                             unsigned short* __restrict__ attnb) {
  const int bh = blockIdx.x >> 4, jb = blockIdx.x & 15;
  const int j0 = jb * 128;
  const int tid = threadIdx.x, w = tid >> 6, l = tid & 63, lg = l >> 4, ll = l & 15;
  __shared__ unsigned short q_lds[2][64 * 64];
  __shared__ unsigned short vt_lds[2][64 * 64];
  __shared__ unsigned short p_lds[128 * 64];
  const unsigned short* q_base = q_g + (size_t)bh * 2048 * 64;
  const unsigned short* vt_base = vt_g + (size_t)bh * 64 * 2048;
  // K A-frags: set0 rows j0+w*32+ll, set1 rows j0+w*32+16+ll
  const unsigned short* krow = k_g + ((size_t)(bh * 2048 + j0 + w * 32 + ll)) * 64;
  const bf16x8 ka00 = *(const bf16x8*)(krow + lg * 8);
  const bf16x8 ka01 = *(const bf16x8*)(krow + 32 + lg * 8);
  const bf16x8 ka10 = *(const bf16x8*)(krow + 1024 + lg * 8);
  const bf16x8 ka11 = *(const bf16x8*)(krow + 1024 + 32 + lg * 8);
  float k2v0[4], k2v1[4];
#pragma unroll
  for (int r = 0; r < 4; ++r) {
    k2v0[r] = k2l_g[bh * 2048 + j0 + w * 32 + lg * 4 + r];
    k2v1[r] = k2l_g[bh * 2048 + j0 + w * 32 + 16 + lg * 4 + r];
  }
  f32x4 oacc0[4] = {};
  f32x4 oacc1[4] = {};
  // prologue: stage it=0 into buf 0
#pragma unroll
  for (int c = 0; c < 2; ++c) {
    const int cc_base = c * 256 + w * 64;
    const int cc = cc_base + l;
    const int row = cc >> 3, cl = cc & 7;
    const int csw = (cl ^ (row & 7)) * 8;
    gl_lds16(q_base + (size_t)row * 64 + csw, &q_lds[0][cc_base * 8]);
    gl_lds16(vt_base + (size_t)row * 2048 + csw, &vt_lds[0][cc_base * 8]);
  }
  __syncthreads();
  for (int it = 0; it < 32; ++it) {
    const int slot = it & 1;
    if (it + 1 < 32) {
      const int i1 = (it + 1) * 64;
#pragma unroll
      for (int c = 0; c < 2; ++c) {
        const int cc_base = c * 256 + w * 64;
        const int cc = cc_base + l;
        const int row = cc >> 3, cl = cc & 7;
        const int csw = (cl ^ (row & 7)) * 8;
        gl_lds16(q_base + (size_t)(i1 + row) * 64 + csw, &q_lds[slot ^ 1][cc_base * 8]);
        gl_lds16(vt_base + (size_t)row * 2048 + i1 + csw, &vt_lds[slot ^ 1][cc_base * 8]);
      }
    }
    // scores ST[j,i] for both j-sets; P^T -> p_lds (truncating bf16 store)
#pragma unroll
    for (int nf = 0; nf < 4; ++nf) {
      const int ir = nf * 16 + ll;
      const unsigned short* qb = &q_lds[slot][ir * 64];
      const int sw = ir & 7;
      bf16x8 b0 = *(const bf16x8*)(qb + ((lg ^ sw) * 8));
      bf16x8 b1 = *(const bf16x8*)(qb + (((4 + lg) ^ sw) * 8));
      f32x4 sa0 = {};
      sa0 = MFMA16(ka00, b0, sa0, 0, 0, 0);
      sa0 = MFMA16(ka01, b1, sa0, 0, 0, 0);
      f32x4 sa1 = {};
      sa1 = MFMA16(ka10, b0, sa1, 0, 0, 0);
      sa1 = MFMA16(ka11, b1, sa1, 0, 0, 0);
#pragma unroll
      for (int r = 0; r < 4; ++r) {
        const float p0 = fexp2(sa0[r] - k2v0[r]);
        const float p1 = fexp2(sa1[r] - k2v1[r]);
        const int ja = w * 32 + lg * 4 + r;
        const int jb2 = ja + 16;
        p_lds[ja * 64 + (ir ^ ((ja & 7) << 3))] =
            (unsigned short)(__float_as_uint(p0) >> 16);
        p_lds[jb2 * 64 + (ir ^ ((jb2 & 7) << 3))] =
            (unsigned short)(__float_as_uint(p1) >> 16);
      }
    }
    // PV: A = P^T rows for both sets (within-wave LDS dependency, no barrier)
    {
      const int jr0 = w * 32 + ll;
      const int jr1 = jr0 + 16;
      const int swp = ll & 7;
      const unsigned short* pb0 = p_lds + jr0 * 64;
      const unsigned short* pb1 = p_lds + jr1 * 64;
      bf16x8 pa00 = *(const bf16x8*)(pb0 + ((lg ^ swp) * 8));
      bf16x8 pa01 = *(const bf16x8*)(pb0 + (((4 + lg) ^ swp) * 8));
      bf16x8 pa10 = *(const bf16x8*)(pb1 + ((lg ^ swp) * 8));
      bf16x8 pa11 = *(const bf16x8*)(pb1 + (((4 + lg) ^ swp) * 8));
#pragma unroll
      for (int nf = 0; nf < 4; ++nf) {
        const int dr = nf * 16 + ll;
        const unsigned short* vb = &vt_lds[slot][dr * 64];
        const int sw = dr & 7;
        bf16x8 v0 = *(const bf16x8*)(vb + ((lg ^ sw) * 8));
        bf16x8 v1 = *(const bf16x8*)(vb + (((4 + lg) ^ sw) * 8));
        oacc0[nf] = MFMA16(pa00, v0, oacc0[nf], 0, 0, 0);
        oacc0[nf] = MFMA16(pa01, v1, oacc0[nf], 0, 0, 0);
        oacc1[nf] = MFMA16(pa10, v0, oacc1[nf], 0, 0, 0);
        oacc1[nf] = MFMA16(pa11, v1, oacc1[nf], 0, 0, 0);
      }
    }
    __syncthreads();
  }
  const int b = bh >> 3, h2 = bh & 7;
#pragma unroll
  for (int nf = 0; nf < 4; ++nf) {
    const int d = nf * 16 + ll;
#pragma unroll
    for (int r = 0; r < 4; ++r) {
      const int j = j0 + w * 32 + lg * 4 + r;
      attnb[((size_t)(b * 2048 + j)) * 512 + h2 * 64 + d] = f2bf(oacc0[nf][r]);
      attnb[((size_t)(b * 2048 + j + 16)) * 512 + h2 * 64 + d] = f2bf(oacc1[nf][r]);
    }
  }
}

// ---------------------------------------------------------------------------
extern "C" void kernel_launch(void* const* d_in, const int* in_sizes, int n_in,
                              void* d_out, int out_size, void* d_ws, size_t ws_size,
                              hipStream_t stream) {
  const float* x  = (const float*)d_in[0];
  const float* Wq = (const float*)d_in[1];
  const float* bq = (const float*)d_in[2];
  const float* Wk = (const float*)d_in[3];
  const float* bk = (const float*)d_in[4];
  const float* Wv = (const float*)d_in[5];
  const float* bv = (const float*)d_in[6];
  const float* Wo = (const float*)d_in[7];
  const float* bo = (const float*)d_in[8];
  float* out = (float*)d_out;
  char* ws = (char*)d_ws;

  unsigned short* xb    = (unsigned short*)(ws);
  unsigned short* wqkvT = (unsigned short*)(ws + 8388608);
  unsigned short* woT   = (unsigned short*)(ws + 9961472);
  float*          biasp = (float*)         (ws + 10485760);
  unsigned short* q_g   = (unsigned short*)(ws + 10493952);
  unsigned short* k_g   = (unsigned short*)(ws + 18882560);
  unsigned short* v_g   = (unsigned short*)(ws + 27271168);
  unsigned short* vt_g  = (unsigned short*)(ws + 35659776);
  float*          k2_g  = (float*)         (ws + 44048384);
  float*          invl_g= (float*)         (ws + 44310528);
  unsigned short* attnb = (unsigned short*)(ws + 44572672);
  if (ws_size < (size_t)52961280) return;

  prep<<<8199, 256, 0, stream>>>(x, Wq, Wk, Wv, Wo, bq, bk, bv, xb, wqkvT, woT, biasp);
  gemm_bt<0><<<dim3(12, 64), 256, 0, stream>>>(xb, wqkvT, biasp, q_g, k_g, v_g, nullptr, 512);
  k2_kernel<<<1024, 256, 0, stream>>>(k_g, k2_g);
  pass1<<<1024, 256, 0, stream>>>(q_g, k_g, k2_g, invl_g);
  transpose_v<<<1024, 256, 0, stream>>>(v_g, invl_g, vt_g);
  pass2<<<512, 256, 0, stream>>>(q_g, k_g, vt_g, k2_g, attnb);
  gemm_bt<1><<<dim3(4, 64), 256, 0, stream>>>(attnb, woT, bo, nullptr, nullptr, nullptr, out, 512);
}

// Round 10
// 161.926 us; speedup vs baseline: 1.0367x; 1.0191x over previous
//
#include <hip/hip_runtime.h>

// ---------------------------------------------------------------------------
// SelfAttention (distance-based, transposed accumulation), MI355X bf16 MFMA.
// B=4, S=2048, F=512, H=8, DH=64, OUT=512.
//
// ROUND 10 = ROUND 9 with:
//  - pass2 i-split x2: grid (512,2); split by=0 sums i-tiles 0..15 -> partial0
//    (attnb region), by=1 sums 16..31 -> partial1 (dead xb region, exact fit).
//    combine kernel adds partials into attnb. Restores 3-4 blocks/CU.
//  - pass1 pack-2 (the r9-validated pattern: two persistent A-frag sets
//    sharing LDS B-operand reads). Grid 512.
// Everything else byte-identical to round 9.
// ---------------------------------------------------------------------------

typedef __attribute__((ext_vector_type(8))) short bf16x8;
typedef __attribute__((ext_vector_type(4))) float f32x4;
typedef __attribute__((ext_vector_type(4))) unsigned short u16x4;

#define MFMA16 __builtin_amdgcn_mfma_f32_16x16x32_bf16
#define LOG2E 1.4426950408889634f
#define TWO_LOG2E 2.8853900817779268f

__device__ inline unsigned short f2bf(float f) {
  unsigned int u = __float_as_uint(f);
  unsigned int r = 0x7fffu + ((u >> 16) & 1u);
  return (unsigned short)((u + r) >> 16);
}
__device__ inline float bf2f(unsigned short h) {
  return __uint_as_float(((unsigned int)h) << 16);
}
__device__ inline float fexp2(float x) { return __builtin_amdgcn_exp2f(x); }

// async global->LDS, 16B per lane. lds base must be wave-uniform.
__device__ inline void gl_lds16(const unsigned short* g, unsigned short* lds) {
  __builtin_amdgcn_global_load_lds(
      (const __attribute__((address_space(1))) unsigned int*)g,
      (__attribute__((address_space(3))) unsigned int*)lds, 16, 0, 0);
}

// ---------------------------------------------------------------------------
// prep: cast x to bf16 (vectorized x4), pack W^T for qkv/out proj, biases.
// (round 9 verbatim)
// ---------------------------------------------------------------------------
#define NXB4 (8192*512/4)
#define NWQ (1536*512)
#define NWO (512*512)

__global__ __launch_bounds__(256) void prep(
    const float* __restrict__ x, const float* __restrict__ Wq,
    const float* __restrict__ Wk, const float* __restrict__ Wv,
    const float* __restrict__ Wo, const float* __restrict__ bq,
    const float* __restrict__ bk, const float* __restrict__ bv,
    unsigned short* __restrict__ xb, unsigned short* __restrict__ wqkvT,
    unsigned short* __restrict__ woT, float* __restrict__ biasp) {
  int i = blockIdx.x * blockDim.x + threadIdx.x;
  if (i < NXB4) {
    f32x4 v = ((const f32x4*)x)[i];
    u16x4 o;
    o.x = f2bf(v.x); o.y = f2bf(v.y); o.z = f2bf(v.z); o.w = f2bf(v.w);
    ((u16x4*)xb)[i] = o;
    return;
  }
  i -= NXB4;
  if (i < NWQ) {  // wqkvT[n][f] = W(f, n%512), n in [0,1536)
    int n = i >> 9, f = i & 511;
    const float* W = (n < 512) ? Wq : (n < 1024) ? Wk : Wv;
    wqkvT[i] = f2bf(W[f * 512 + (n & 511)]);
    return;
  }
  i -= NWQ;
  if (i < NWO) {  // woT[o][hd] = Wo[hd][o]
    int o = i >> 9, hd = i & 511;
    woT[i] = f2bf(Wo[hd * 512 + o]);
    return;
  }
  i -= NWO;
  if (i < 1536) {
    biasp[i] = (i < 512) ? bq[i] : (i < 1024) ? bk[i - 512] : bv[i - 1024];
  }
}

// ---------------------------------------------------------------------------
// GEMM C[M,N] = A[M,K] * Bt[N,K]^T + bias (round 9 verbatim).
// MODE 0: scatter bf16 into q~/k/v [bh][s][d].  MODE 1: bias+leakyrelu f32.
// ---------------------------------------------------------------------------
template<int MODE>
__global__ __launch_bounds__(256) void gemm_bt(
    const unsigned short* __restrict__ A, const unsigned short* __restrict__ Bt,
    const float* __restrict__ bias,
    unsigned short* __restrict__ o_q, unsigned short* __restrict__ o_k,
    unsigned short* __restrict__ o_v, float* __restrict__ o_f, int K) {
  const int m0 = blockIdx.y * 128;
  const int n0 = blockIdx.x * 128;
  const int tid = threadIdx.x;
  const int w = tid >> 6, l = tid & 63, lg = l >> 4, ll = l & 15;
  const int wr = w >> 1, wc = w & 1;
  __shared__ unsigned short a_lds[128 * 32];
  __shared__ unsigned short b_lds[128 * 32];
  f32x4 acc[4][4] = {};
  const int nkt = K >> 5;
  for (int kt = 0; kt < nkt; ++kt) {
#pragma unroll
    for (int c = 0; c < 2; ++c) {
      const int cc_base = c * 256 + w * 64;
      const int cc = cc_base + l;
      const int row = cc >> 2, cl = cc & 3;
      gl_lds16(A + (size_t)(m0 + row) * K + kt * 32 + cl * 8, a_lds + cc_base * 8);
      gl_lds16(Bt + (size_t)(n0 + row) * K + kt * 32 + cl * 8, b_lds + cc_base * 8);
    }
    __syncthreads();
    bf16x8 af[4], bfr[4];
#pragma unroll
    for (int mi = 0; mi < 4; ++mi)
      af[mi] = *(const bf16x8*)(a_lds + (wr * 64 + mi * 16 + ll) * 32 + lg * 8);
#pragma unroll
    for (int ni = 0; ni < 4; ++ni)
      bfr[ni] = *(const bf16x8*)(b_lds + (wc * 64 + ni * 16 + ll) * 32 + lg * 8);
#pragma unroll
    for (int mi = 0; mi < 4; ++mi)
#pragma unroll
      for (int ni = 0; ni < 4; ++ni)
        acc[mi][ni] = MFMA16(af[mi], bfr[ni], acc[mi][ni], 0, 0, 0);
    __syncthreads();
  }
#pragma unroll
  for (int mi = 0; mi < 4; ++mi)
#pragma unroll
    for (int ni = 0; ni < 4; ++ni) {
      const int col = n0 + wc * 64 + ni * 16 + ll;
      const float bb = bias[col];
#pragma unroll
      for (int r = 0; r < 4; ++r) {
        const int row = m0 + wr * 64 + mi * 16 + lg * 4 + r;
        float v = acc[mi][ni][r] + bb;
        if (MODE == 0) {
          const int which = col >> 9, h = (col >> 6) & 7, d = col & 63;
          const int b = row >> 11, s = row & 2047;
          if (which == 0) v *= TWO_LOG2E;  // q prescale
          const size_t idx = ((size_t)((b * 8 + h) * 2048 + s)) * 64 + d;
          (which == 0 ? o_q : which == 1 ? o_k : o_v)[idx] = f2bf(v);
        } else {
          v = v >= 0.f ? v : 0.01f * v;
          o_f[(size_t)row * 512 + col] = v;
        }
      }
    }
}

// ---------------------------------------------------------------------------
// k2l[row] = log2e * sum_d k[row][d]^2   (round 9 verbatim)
// ---------------------------------------------------------------------------
__global__ __launch_bounds__(256) void k2_kernel(const unsigned short* __restrict__ k_g,
                                                 float* __restrict__ k2l_g) {
  const int lane = threadIdx.x & 63;
  const int wid = (blockIdx.x * blockDim.x + threadIdx.x) >> 6;
  const int nw = (gridDim.x * blockDim.x) >> 6;
  for (int row = wid; row < 32 * 2048; row += nw) {
    float v = bf2f(k_g[(size_t)row * 64 + lane]);
    v *= v;
#pragma unroll
    for (int m = 1; m < 64; m <<= 1) v += __shfl_xor(v, m);
    if (lane == 0) k2l_g[row] = LOG2E * v;
  }
}

// ---------------------------------------------------------------------------
// transpose_v: vT~[bh][d][s] = invl[s] * v[bh][s][d]  (round 9 verbatim)
// ---------------------------------------------------------------------------
__global__ __launch_bounds__(256) void transpose_v(const unsigned short* __restrict__ v_g,
                                                   const float* __restrict__ invl_g,
                                                   unsigned short* __restrict__ vt_g) {
  const int bh = blockIdx.x >> 5, st = blockIdx.x & 31;
  const int s0 = st * 64;
  __shared__ unsigned short tile[64][72];
  const int t = threadIdx.x;
  {
    const int sl = t >> 2, cg = t & 3;
    const float sc = invl_g[bh * 2048 + s0 + sl];
    const unsigned short* src = v_g + ((size_t)(bh * 2048 + s0 + sl)) * 64 + cg * 16;
    bf16x8 v0 = *(const bf16x8*)(src);
    bf16x8 v1 = *(const bf16x8*)(src + 8);
#pragma unroll
    for (int e = 0; e < 8; ++e) tile[sl][cg * 16 + e] = f2bf(sc * bf2f((unsigned short)v0[e]));
#pragma unroll
    for (int e = 0; e < 8; ++e) tile[sl][cg * 16 + 8 + e] = f2bf(sc * bf2f((unsigned short)v1[e]));
  }
  __syncthreads();
  {
    const int dl = t >> 2, sg = t & 3;
    bf16x8 o0, o1;
#pragma unroll
    for (int e = 0; e < 8; ++e) o0[e] = (short)tile[sg * 16 + e][dl];
#pragma unroll
    for (int e = 0; e < 8; ++e) o1[e] = (short)tile[sg * 16 + 8 + e][dl];
    unsigned short* dst = vt_g + ((size_t)(bh * 64 + dl)) * 2048 + s0 + sg * 16;
    *(bf16x8*)dst = o0;
    *(bf16x8*)(dst + 8) = o1;
  }
}

// ---------------------------------------------------------------------------
// pass1: invl[i] = 1 / sum_j exp2(q~_i.k_j - k2l[j])
// PACK-2 (r9-validated pattern): 4 waves x 32 i = 128 i per block, two
// persistent Q A-frag sets sharing the LDS K B-operand reads. Grid 512.
// Staging/sync byte-identical to round 9's pass1.
// ---------------------------------------------------------------------------
__global__ __launch_bounds__(256) void pass1(const unsigned short* __restrict__ q_g,
                                             const unsigned short* __restrict__ k_g,
                                             const float* __restrict__ k2l_g,
                                             float* __restrict__ invl_g) {
  const int bh = blockIdx.x >> 4, ib = blockIdx.x & 15;
  const int i0 = ib * 128;
  const int tid = threadIdx.x, w = tid >> 6, l = tid & 63, lg = l >> 4, ll = l & 15;
  __shared__ unsigned short k_lds[64 * 64];
  __shared__ float k2_lds[64];
  const unsigned short* qrow = q_g + ((size_t)(bh * 2048 + i0 + w * 32 + ll)) * 64;
  const bf16x8 qa00 = *(const bf16x8*)(qrow + lg * 8);
  const bf16x8 qa01 = *(const bf16x8*)(qrow + 32 + lg * 8);
  const bf16x8 qa10 = *(const bf16x8*)(qrow + 1024 + lg * 8);
  const bf16x8 qa11 = *(const bf16x8*)(qrow + 1024 + 32 + lg * 8);
  float lrun0[4] = {0.f, 0.f, 0.f, 0.f};
  float lrun1[4] = {0.f, 0.f, 0.f, 0.f};
  for (int jt = 0; jt < 32; ++jt) {
    const int j0 = jt * 64;
#pragma unroll
    for (int c = 0; c < 2; ++c) {
      const int cc_base = c * 256 + w * 64;
      const int cc = cc_base + l;
      const int row = cc >> 3, cl = cc & 7;
      gl_lds16(k_g + ((size_t)(bh * 2048 + j0 + row)) * 64 + ((cl ^ (row & 7)) * 8),
               k_lds + cc_base * 8);
    }
    if (tid < 64) k2_lds[tid] = k2l_g[bh * 2048 + j0 + tid];
    __syncthreads();
#pragma unroll
    for (int nf = 0; nf < 4; ++nf) {
      const int jr = nf * 16 + ll;
      const unsigned short* kb = k_lds + jr * 64;
      const int sw = jr & 7;
      bf16x8 b0 = *(const bf16x8*)(kb + ((lg ^ sw) * 8));
      bf16x8 b1 = *(const bf16x8*)(kb + (((4 + lg) ^ sw) * 8));
      f32x4 sa0 = {};
      sa0 = MFMA16(qa00, b0, sa0, 0, 0, 0);
      sa0 = MFMA16(qa01, b1, sa0, 0, 0, 0);
      f32x4 sa1 = {};
      sa1 = MFMA16(qa10, b0, sa1, 0, 0, 0);
      sa1 = MFMA16(qa11, b1, sa1, 0, 0, 0);
      const float k2v = k2_lds[jr];
      lrun0[0] += fexp2(sa0[0] - k2v);
      lrun0[1] += fexp2(sa0[1] - k2v);
      lrun0[2] += fexp2(sa0[2] - k2v);
      lrun0[3] += fexp2(sa0[3] - k2v);
      lrun1[0] += fexp2(sa1[0] - k2v);
      lrun1[1] += fexp2(sa1[1] - k2v);
      lrun1[2] += fexp2(sa1[2] - k2v);
      lrun1[3] += fexp2(sa1[3] - k2v);
    }
    __syncthreads();
  }
#pragma unroll
  for (int r = 0; r < 4; ++r) {
    float t0 = lrun0[r], t1 = lrun1[r];
#pragma unroll
    for (int m = 1; m < 16; m <<= 1) { t0 += __shfl_xor(t0, m); t1 += __shfl_xor(t1, m); }
    if (ll == 0) {
      invl_g[bh * 2048 + i0 + w * 32 + lg * 4 + r] = 1.f / t0;
      invl_g[bh * 2048 + i0 + w * 32 + 16 + lg * 4 + r] = 1.f / t1;
    }
  }
}

// ---------------------------------------------------------------------------
// pass2: attn[j,d] = sum_i exp2(q~_i.k_j - k2l[j]) * v~[i,d]
// Round-9 pack-2 body + i-split: blockIdx.y in {0,1} selects i-tiles
// [16*by, 16*by+16); output goes to part0 (by=0) or part1 (by=1) as bf16
// partials. Both splits start at even it -> prologue slot parity unchanged.
// ---------------------------------------------------------------------------
__global__ __launch_bounds__(256) void pass2(const unsigned short* __restrict__ q_g,
                                             const unsigned short* __restrict__ k_g,
                                             const unsigned short* __restrict__ vt_g,
                                             const float* __restrict__ k2l_g,
                                             unsigned short* __restrict__ part0,
                                             unsigned short* __restrict__ part1) {
  const int bh = blockIdx.x >> 4, jb = blockIdx.x & 15;
  const int by = blockIdx.y;
  const int j0 = jb * 128;
  const int it0 = by << 4, it_end = it0 + 16;
  const int tid = threadIdx.x, w = tid >> 6, l = tid & 63, lg = l >> 4, ll = l & 15;
  __shared__ unsigned short q_lds[2][64 * 64];
  __shared__ unsigned short vt_lds[2][64 * 64];
  __shared__ unsigned short p_lds[128 * 64];
  const unsigned short* q_base = q_g + (size_t)bh * 2048 * 64;
  const unsigned short* vt_base = vt_g + (size_t)bh * 64 * 2048;
  // K A-frags: set0 rows j0+w*32+ll, set1 rows j0+w*32+16+ll
  const unsigned short* krow = k_g + ((size_t)(bh * 2048 + j0 + w * 32 + ll)) * 64;
  const bf16x8 ka00 = *(const bf16x8*)(krow + lg * 8);
  const bf16x8 ka01 = *(const bf16x8*)(krow + 32 + lg * 8);
  const bf16x8 ka10 = *(const bf16x8*)(krow + 1024 + lg * 8);
  const bf16x8 ka11 = *(const bf16x8*)(krow + 1024 + 32 + lg * 8);
  float k2v0[4], k2v1[4];
#pragma unroll
  for (int r = 0; r < 4; ++r) {
    k2v0[r] = k2l_g[bh * 2048 + j0 + w * 32 + lg * 4 + r];
    k2v1[r] = k2l_g[bh * 2048 + j0 + w * 32 + 16 + lg * 4 + r];
  }
  f32x4 oacc0[4] = {};
  f32x4 oacc1[4] = {};
  // prologue: stage tile it0 into buf 0
#pragma unroll
  for (int c = 0; c < 2; ++c) {
    const int cc_base = c * 256 + w * 64;
    const int cc = cc_base + l;
    const int row = cc >> 3, cl = cc & 7;
    const int csw = (cl ^ (row & 7)) * 8;
    gl_lds16(q_base + (size_t)(it0 * 64 + row) * 64 + csw, &q_lds[0][cc_base * 8]);
    gl_lds16(vt_base + (size_t)row * 2048 + it0 * 64 + csw, &vt_lds[0][cc_base * 8]);
  }
  __syncthreads();
  for (int it = it0; it < it_end; ++it) {
    const int slot = it & 1;
    if (it + 1 < it_end) {
      const int i1 = (it + 1) * 64;
#pragma unroll
      for (int c = 0; c < 2; ++c) {
        const int cc_base = c * 256 + w * 64;
        const int cc = cc_base + l;
        const int row = cc >> 3, cl = cc & 7;
        const int csw = (cl ^ (row & 7)) * 8;
        gl_lds16(q_base + (size_t)(i1 + row) * 64 + csw, &q_lds[slot ^ 1][cc_base * 8]);
        gl_lds16(vt_base + (size_t)row * 2048 + i1 + csw, &vt_lds[slot ^ 1][cc_base * 8]);
      }
    }
    // scores ST[j,i] for both j-sets; P^T -> p_lds (truncating bf16 store)
#pragma unroll
    for (int nf = 0; nf < 4; ++nf) {
      const int ir = nf * 16 + ll;
      const unsigned short* qb = &q_lds[slot][ir * 64];
      const int sw = ir & 7;
      bf16x8 b0 = *(const bf16x8*)(qb + ((lg ^ sw) * 8));
      bf16x8 b1 = *(const bf16x8*)(qb + (((4 + lg) ^ sw) * 8));
      f32x4 sa0 = {};
      sa0 = MFMA16(ka00, b0, sa0, 0, 0, 0);
      sa0 = MFMA16(ka01, b1, sa0, 0, 0, 0);
      f32x4 sa1 = {};
      sa1 = MFMA16(ka10, b0, sa1, 0, 0, 0);
      sa1 = MFMA16(ka11, b1, sa1, 0, 0, 0);
#pragma unroll
      for (int r = 0; r < 4; ++r) {
        const float p0 = fexp2(sa0[r] - k2v0[r]);
        const float p1 = fexp2(sa1[r] - k2v1[r]);
        const int ja = w * 32 + lg * 4 + r;
        const int jb2 = ja + 16;
        p_lds[ja * 64 + (ir ^ ((ja & 7) << 3))] =
            (unsigned short)(__float_as_uint(p0) >> 16);
        p_lds[jb2 * 64 + (ir ^ ((jb2 & 7) << 3))] =
            (unsigned short)(__float_as_uint(p1) >> 16);
      }
    }
    // PV: A = P^T rows for both sets (within-wave LDS dependency, no barrier)
    {
      const int jr0 = w * 32 + ll;
      const int jr1 = jr0 + 16;
      const int swp = ll & 7;
      const unsigned short* pb0 = p_lds + jr0 * 64;
      const unsigned short* pb1 = p_lds + jr1 * 64;
      bf16x8 pa00 = *(const bf16x8*)(pb0 + ((lg ^ swp) * 8));
      bf16x8 pa01 = *(const bf16x8*)(pb0 + (((4 + lg) ^ swp) * 8));
      bf16x8 pa10 = *(const bf16x8*)(pb1 + ((lg ^ swp) * 8));
      bf16x8 pa11 = *(const bf16x8*)(pb1 + (((4 + lg) ^ swp) * 8));
#pragma unroll
      for (int nf = 0; nf < 4; ++nf) {
        const int dr = nf * 16 + ll;
        const unsigned short* vb = &vt_lds[slot][dr * 64];
        const int sw = dr & 7;
        bf16x8 v0 = *(const bf16x8*)(vb + ((lg ^ sw) * 8));
        bf16x8 v1 = *(const bf16x8*)(vb + (((4 + lg) ^ sw) * 8));
        oacc0[nf] = MFMA16(pa00, v0, oacc0[nf], 0, 0, 0);
        oacc0[nf] = MFMA16(pa01, v1, oacc0[nf], 0, 0, 0);
        oacc1[nf] = MFMA16(pa10, v0, oacc1[nf], 0, 0, 0);
        oacc1[nf] = MFMA16(pa11, v1, oacc1[nf], 0, 0, 0);
      }
    }
    __syncthreads();
  }
  unsigned short* po = by ? part1 : part0;
  const int b = bh >> 3, h2 = bh & 7;
#pragma unroll
  for (int nf = 0; nf < 4; ++nf) {
    const int d = nf * 16 + ll;
#pragma unroll
    for (int r = 0; r < 4; ++r) {
      const int j = j0 + w * 32 + lg * 4 + r;
      po[((size_t)(b * 2048 + j)) * 512 + h2 * 64 + d] = f2bf(oacc0[nf][r]);
      po[((size_t)(b * 2048 + j + 16)) * 512 + h2 * 64 + d] = f2bf(oacc1[nf][r]);
    }
  }
}

// ---------------------------------------------------------------------------
// combine: attnb = bf16(part0 + part1), in place over part0. 4.2M elems.
// ---------------------------------------------------------------------------
__global__ __launch_bounds__(256) void combine(unsigned short* __restrict__ p0,
                                               const unsigned short* __restrict__ p1) {
  const int i = blockIdx.x * blockDim.x + threadIdx.x;  // ushort8 units
  bf16x8 a = ((const bf16x8*)p0)[i];
  bf16x8 b = ((const bf16x8*)p1)[i];
  bf16x8 o;
#pragma unroll
  for (int e = 0; e < 8; ++e)
    o[e] = (short)f2bf(bf2f((unsigned short)a[e]) + bf2f((unsigned short)b[e]));
  ((bf16x8*)p0)[i] = o;
}

// ---------------------------------------------------------------------------
extern "C" void kernel_launch(void* const* d_in, const int* in_sizes, int n_in,
                              void* d_out, int out_size, void* d_ws, size_t ws_size,
                              hipStream_t stream) {
  const float* x  = (const float*)d_in[0];
  const float* Wq = (const float*)d_in[1];
  const float* bq = (const float*)d_in[2];
  const float* Wk = (const float*)d_in[3];
  const float* bk = (const float*)d_in[4];
  const float* Wv = (const float*)d_in[5];
  const float* bv = (const float*)d_in[6];
  const float* Wo = (const float*)d_in[7];
  const float* bo = (const float*)d_in[8];
  float* out = (float*)d_out;
  char* ws = (char*)d_ws;

  unsigned short* xb    = (unsigned short*)(ws);          // also pass2 part1
  unsigned short* wqkvT = (unsigned short*)(ws + 8388608);
  unsigned short* woT   = (unsigned short*)(ws + 9961472);
  float*          biasp = (float*)         (ws + 10485760);
  unsigned short* q_g   = (unsigned short*)(ws + 10493952);
  unsigned short* k_g   = (unsigned short*)(ws + 18882560);
  unsigned short* v_g   = (unsigned short*)(ws + 27271168);
  unsigned short* vt_g  = (unsigned short*)(ws + 35659776);
  float*          k2_g  = (float*)         (ws + 44048384);
  float*          invl_g= (float*)         (ws + 44310528);
  unsigned short* attnb = (unsigned short*)(ws + 44572672);  // pass2 part0
  if (ws_size < (size_t)52961280) return;

  prep<<<8199, 256, 0, stream>>>(x, Wq, Wk, Wv, Wo, bq, bk, bv, xb, wqkvT, woT, biasp);
  gemm_bt<0><<<dim3(12, 64), 256, 0, stream>>>(xb, wqkvT, biasp, q_g, k_g, v_g, nullptr, 512);
  k2_kernel<<<1024, 256, 0, stream>>>(k_g, k2_g);
  pass1<<<512, 256, 0, stream>>>(q_g, k_g, k2_g, invl_g);
  transpose_v<<<1024, 256, 0, stream>>>(v_g, invl_g, vt_g);
  pass2<<<dim3(512, 2), 256, 0, stream>>>(q_g, k_g, vt_g, k2_g, attnb, xb);
  combine<<<2048, 256, 0, stream>>>(attnb, xb);
  gemm_bt<1><<<dim3(4, 64), 256, 0, stream>>>(attnb, woT, bo, nullptr, nullptr, nullptr, out, 512);
}